// Round 1
// 244.444 us; speedup vs baseline: 1.2051x; 1.2051x over previous
//
#include <hip/hip_runtime.h>
#include <hip/hip_bf16.h>

#define N_NODES 100000
#define N_EDGES 1250000
#define HID 64
#define LDSS 72       // LDS row stride in bf16 elems: 64 + 8 pad (144 B rows)
#define NB 196        // buckets of 512 node-ids: (100000+511)/512
#define NBLOCK 128    // edge-slice blocks for P1/P3
#define EMB_BLOCKS 6250  // N_NODES*16/256 exactly

typedef __bf16 bf16x8 __attribute__((ext_vector_type(8)));
typedef float  f32x4  __attribute__((ext_vector_type(4)));

__device__ __forceinline__ float bflo(uint u) {   // low bf16 of packed uint -> f32
    union { unsigned int i; float f; } v; v.i = u << 16; return v.f;
}
__device__ __forceinline__ float bfhi(uint u) {   // high bf16 -> f32
    union { unsigned int i; float f; } v; v.i = u & 0xFFFF0000u; return v.f;
}
__device__ __forceinline__ ushort f2bf(float f) {
    union { float f; unsigned int i; } v; v.f = f;
    unsigned int x = v.i;
    return (ushort)((x + 0x7fffu + ((x >> 16) & 1u)) >> 16);  // RNE
}

// Fused prep: blocks [0,6250) embed-gather, [6250,6378) edge histogram,
// [6378,6383) weight convert. All three are independent -> overlap on-chip.
__global__ __launch_bounds__(256) void prep(const int* __restrict__ x,
                                            const float* __restrict__ emb,
                                            ushort* __restrict__ h0,
                                            const int* __restrict__ dst,
                                            int* __restrict__ gh,
                                            const float* __restrict__ Wl1,
                                            const float* __restrict__ Wr1,
                                            const float* __restrict__ Wl2,
                                            const float* __restrict__ Wr2,
                                            const float* __restrict__ Wout,
                                            ushort* __restrict__ wbf) {
    const int b = blockIdx.x;
    const int tid = threadIdx.x;
    if (b < EMB_BLOCKS) {
        // h0[i][:] = bf16(emb[x[i]][:]); 16 threads/row, float4 each
        int t = b * 256 + tid;
        int row = t >> 4, c = t & 15;
        int idx = x[row];
        float4 v = ((const float4*)(emb + (size_t)idx * HID))[c];
        ushort4 w;
        w.x = f2bf(v.x); w.y = f2bf(v.y); w.z = f2bf(v.z); w.w = f2bf(v.w);
        ((ushort4*)(h0 + (size_t)row * HID))[c] = w;
    } else if (b < EMB_BLOCKS + NBLOCK) {
        __shared__ int hist[NB];
        const int bb = b - EMB_BLOCKS;
        for (int i = tid; i < NB; i += 256) hist[i] = 0;
        __syncthreads();
        const int4* d4 = (const int4*)dst;            // N_EDGES % 4 == 0
        for (int e = bb * 256 + tid; e < N_EDGES / 4; e += NBLOCK * 256) {
            int4 v = d4[e];
            atomicAdd(&hist[v.x >> 9], 1);
            atomicAdd(&hist[v.y >> 9], 1);
            atomicAdd(&hist[v.z >> 9], 1);
            atomicAdd(&hist[v.w >> 9], 1);
        }
        __syncthreads();
        for (int i = tid; i < NB; i += 256) gh[bb * NB + i] = hist[i];
    } else {
        // wbf[m][n*64+k] = bf16(W_m[k*64+n]) (transposed)
        const int wb = b - EMB_BLOCKS - NBLOCK;
        const float* W = (wb == 0) ? Wl1 : (wb == 1) ? Wr1 :
                         (wb == 2) ? Wl2 : (wb == 3) ? Wr2 : Wout;
        ushort* o = wbf + wb * 4096;
        for (int idx = tid; idx < 4096; idx += 256) {
            int k = idx >> 6, n = idx & 63;
            o[n * 64 + k] = f2bf(W[idx]);
        }
    }
}

// Per-bucket exclusive scan over the 128 per-block counts (unchanged).
__global__ __launch_bounds__(128) void p2_scan(int* __restrict__ gh,
                                               int* __restrict__ btot) {
    __shared__ int w0tot;
    const int v = blockIdx.x;
    const int t = threadIdx.x, lane = t & 63, wave = t >> 6;
    int val = gh[t * NB + v];
    int x = val;
#pragma unroll
    for (int d = 1; d < 64; d <<= 1) {
        int y = __shfl_up(x, d, 64);
        if (lane >= d) x += y;
    }
    if (wave == 0 && lane == 63) w0tot = x;
    __syncthreads();
    int excl = (x - val) + (wave == 1 ? w0tot : 0);
    gh[t * NB + v] = excl;
    if (wave == 1 && lane == 63) btot[v] = excl + val;
}

// Scatter into bucket-sorted ebuf. The 196-bucket exclusive scan of btot is
// recomputed in-block (~200 cycles) instead of a separate p2b launch;
// block 0 publishes bstart for p4.
__global__ __launch_bounds__(256) void p3_scatter(const int* __restrict__ src,
                                                  const int* __restrict__ dst,
                                                  const int* __restrict__ gh,
                                                  const int* __restrict__ btot,
                                                  int* __restrict__ bstart,
                                                  uint* __restrict__ ebuf) {
    __shared__ int base[NB];
    __shared__ int run[NB];
    __shared__ int wsum[4];
    const int tid = threadIdx.x, lane = tid & 63, wave = tid >> 6;
    int v = (tid < NB) ? btot[tid] : 0;
    int xs = v;
#pragma unroll
    for (int d = 1; d < 64; d <<= 1) {
        int y = __shfl_up(xs, d, 64);
        if (lane >= d) xs += y;
    }
    if (lane == 63) wsum[wave] = xs;
    __syncthreads();
    if (wave == 0) {
        int s = (lane < 4) ? wsum[lane] : 0;
#pragma unroll
        for (int d = 1; d < 4; d <<= 1) {
            int y = __shfl_up(s, d, 64);
            if (lane >= d) s += y;
        }
        if (lane < 4) wsum[lane] = s;
    }
    __syncthreads();
    int waveoff = (wave == 0) ? 0 : wsum[wave - 1];
    int excl = waveoff + (xs - v);
    if (tid < NB) {
        base[tid] = excl + gh[blockIdx.x * NB + tid];
        run[tid] = 0;
        if (blockIdx.x == 0) bstart[tid] = excl;
    }
    if (blockIdx.x == 0 && tid == 0) bstart[NB] = N_EDGES;
    __syncthreads();
    const int4* s4 = (const int4*)src;
    const int4* d4 = (const int4*)dst;
    for (int e = blockIdx.x * 256 + tid; e < N_EDGES / 4; e += NBLOCK * 256) {
        int4 dv = d4[e];
        int4 sv = s4[e];
        int b0 = dv.x >> 9;
        int r0 = atomicAdd(&run[b0], 1);
        ebuf[base[b0] + r0] = ((uint)(dv.x & 511) << 17) | (uint)sv.x;
        int b1 = dv.y >> 9;
        int r1 = atomicAdd(&run[b1], 1);
        ebuf[base[b1] + r1] = ((uint)(dv.y & 511) << 17) | (uint)sv.y;
        int b2 = dv.z >> 9;
        int r2 = atomicAdd(&run[b2], 1);
        ebuf[base[b2] + r2] = ((uint)(dv.z & 511) << 17) | (uint)sv.z;
        int b3 = dv.w >> 9;
        int r3 = atomicAdd(&run[b3], 1);
        ebuf[base[b3] + r3] = ((uint)(dv.w & 511) << 17) | (uint)sv.w;
    }
}

__global__ __launch_bounds__(256) void p4_csr(const uint* __restrict__ ebuf,
                                              const int* __restrict__ bstart,
                                              int* __restrict__ rowptr,
                                              int* __restrict__ csr_src) {
    __shared__ int hist[512], hoff[512], run[512];
    __shared__ int wsum[4];
    const int v = blockIdx.x;
    const int tid = threadIdx.x, lane = tid & 63, wave = tid >> 6;
    const int node0 = v << 9;
    const int nn = min(512, N_NODES - node0);
    const int beg = bstart[v], end = bstart[v + 1];

    for (int i = tid; i < 512; i += 256) { hist[i] = 0; run[i] = 0; }
    __syncthreads();
    for (int e = beg + tid; e < end; e += 256)
        atomicAdd(&hist[ebuf[e] >> 17], 1);
    __syncthreads();
    int h0 = hist[2 * tid], h1 = hist[2 * tid + 1];
    int s = h0 + h1;
    int x = s;
#pragma unroll
    for (int d = 1; d < 64; d <<= 1) {
        int y = __shfl_up(x, d, 64);
        if (lane >= d) x += y;
    }
    if (lane == 63) wsum[wave] = x;
    __syncthreads();
    if (wave == 0) {
        int s2 = (lane < 4) ? wsum[lane] : 0;
#pragma unroll
        for (int d = 1; d < 4; d <<= 1) {
            int y = __shfl_up(s2, d, 64);
            if (lane >= d) s2 += y;
        }
        if (lane < 4) wsum[lane] = s2;
    }
    __syncthreads();
    int waveoff = (wave == 0) ? 0 : wsum[wave - 1];
    int excl = waveoff + (x - s);
    hoff[2 * tid] = excl;
    hoff[2 * tid + 1] = excl + h0;
    __syncthreads();
    for (int j = tid; j < nn; j += 256) rowptr[node0 + j] = beg + hoff[j];
    if (v == NB - 1 && tid == 0) rowptr[N_NODES] = N_EDGES;
    for (int e = beg + tid; e < end; e += 256) {
        uint p = ebuf[e];
        int dl = p >> 17;
        int r = atomicAdd(&run[dl], 1);
        csr_src[beg + hoff[dl] + r] = (int)(p & 0x1FFFFu);
    }
}

// Fused layer: aggregate mean of 64 nodes into LDS (bf16), then MFMA GEMM
// out = prelu(mean@Wl + bl + hin@Wr). OUTPROJ additionally keeps h2 in LDS
// and applies @Wout + bout with f32 output (no h2/mean HBM round-trips).
// GEMM A-operands are wave-private rows, so the tile fusion is race-free.
template <bool OUTPROJ>
__global__ __launch_bounds__(256, OUTPROJ ? 3 : 4) void layer_fused(
    const int* __restrict__ rowptr, const int* __restrict__ csr_src,
    const ushort* __restrict__ hin,
    const ushort* __restrict__ wl_bf, const float* __restrict__ bl,
    const ushort* __restrict__ wr_bf, const float* __restrict__ alpha_p,
    const ushort* __restrict__ wo_bf, const float* __restrict__ bo,
    void* __restrict__ out_p) {
    __shared__ __align__(16) ushort sA[64][LDSS];               // mean, then h2
    __shared__ __align__(16) ushort sH[64][LDSS];               // hin rows
    __shared__ __align__(16) ushort sWl[64][LDSS];
    __shared__ __align__(16) ushort sWr[64][LDSS];
    __shared__ __align__(16) ushort sWo[OUTPROJ ? 64 : 1][LDSS];

    const int tid = threadIdx.x;
    const int row0 = blockIdx.x * 64;

    for (int c = tid; c < 512; c += 256) {
        int nr = c >> 3, kc = (c & 7) * 8;
        *(uint4*)&sWr[nr][kc] = *(const uint4*)&wr_bf[nr * 64 + kc];
        *(uint4*)&sWl[nr][kc] = *(const uint4*)&wl_bf[nr * 64 + kc];
        if constexpr (OUTPROJ)
            *(uint4*)&sWo[nr][kc] = *(const uint4*)&wo_bf[nr * 64 + kc];
    }
    for (int c = tid; c < 512; c += 256) {
        int r = c >> 3, dc = (c & 7) * 8;
        int g = row0 + r;
        uint4 hv = {0, 0, 0, 0};
        if (g < N_NODES) hv = *(const uint4*)&hin[(size_t)g * HID + dc];
        *(uint4*)&sH[r][dc] = hv;
    }

    // ---- aggregation: 32 groups x 8 lanes; each group 2 nodes; 4-way MLP unroll
    const int grp = tid >> 3, gg = tid & 7;
    for (int nl = grp; nl < 64; nl += 32) {
        int node = row0 + nl;
        uint4 o = {0, 0, 0, 0};
        if (node < N_NODES) {
            int beg = rowptr[node], end = rowptr[node + 1];
            float a0 = 0.f, a1 = 0.f, a2 = 0.f, a3 = 0.f;
            float a4 = 0.f, a5 = 0.f, a6 = 0.f, a7 = 0.f;
            int i = beg;
            for (; i + 4 <= end; i += 4) {
                int s0 = csr_src[i], s1 = csr_src[i + 1];
                int s2 = csr_src[i + 2], s3 = csr_src[i + 3];
                uint4 w0 = *(const uint4*)&hin[(size_t)s0 * HID + gg * 8];
                uint4 w1 = *(const uint4*)&hin[(size_t)s1 * HID + gg * 8];
                uint4 w2 = *(const uint4*)&hin[(size_t)s2 * HID + gg * 8];
                uint4 w3 = *(const uint4*)&hin[(size_t)s3 * HID + gg * 8];
                a0 += (bflo(w0.x) + bflo(w1.x)) + (bflo(w2.x) + bflo(w3.x));
                a1 += (bfhi(w0.x) + bfhi(w1.x)) + (bfhi(w2.x) + bfhi(w3.x));
                a2 += (bflo(w0.y) + bflo(w1.y)) + (bflo(w2.y) + bflo(w3.y));
                a3 += (bfhi(w0.y) + bfhi(w1.y)) + (bfhi(w2.y) + bfhi(w3.y));
                a4 += (bflo(w0.z) + bflo(w1.z)) + (bflo(w2.z) + bflo(w3.z));
                a5 += (bfhi(w0.z) + bfhi(w1.z)) + (bfhi(w2.z) + bfhi(w3.z));
                a6 += (bflo(w0.w) + bflo(w1.w)) + (bflo(w2.w) + bflo(w3.w));
                a7 += (bfhi(w0.w) + bfhi(w1.w)) + (bfhi(w2.w) + bfhi(w3.w));
            }
            for (; i < end; ++i) {
                int s = csr_src[i];
                uint4 w = *(const uint4*)&hin[(size_t)s * HID + gg * 8];
                a0 += bflo(w.x); a1 += bfhi(w.x);
                a2 += bflo(w.y); a3 += bfhi(w.y);
                a4 += bflo(w.z); a5 += bfhi(w.z);
                a6 += bflo(w.w); a7 += bfhi(w.w);
            }
            float inv = (end > beg) ? 1.0f / (float)(end - beg) : 0.f;
            o.x = (uint)f2bf(a0 * inv) | ((uint)f2bf(a1 * inv) << 16);
            o.y = (uint)f2bf(a2 * inv) | ((uint)f2bf(a3 * inv) << 16);
            o.z = (uint)f2bf(a4 * inv) | ((uint)f2bf(a5 * inv) << 16);
            o.w = (uint)f2bf(a6 * inv) | ((uint)f2bf(a7 * inv) << 16);
        }
        *(uint4*)&sA[nl][gg * 8] = o;
    }
    __syncthreads();

    // ---- MFMA: 64 rows, 4 waves x 16 rows; 4 col-tiles of 16
    const int wave = tid >> 6, lane = tid & 63;
    const int quad = lane >> 4, lr = lane & 15;
    const int r0 = wave * 16;
    const float alpha = alpha_p[0];

    f32x4 acc[4];
#pragma unroll
    for (int nt = 0; nt < 4; ++nt) {
        f32x4 a = {0.f, 0.f, 0.f, 0.f};
#pragma unroll
        for (int ks = 0; ks < 2; ++ks) {
            int k0 = ks * 32 + quad * 8;
            bf16x8 hf = *(const bf16x8*)&sH[r0 + lr][k0];
            bf16x8 wr = *(const bf16x8*)&sWr[nt * 16 + lr][k0];
            a = __builtin_amdgcn_mfma_f32_16x16x32_bf16(hf, wr, a, 0, 0, 0);
            bf16x8 af = *(const bf16x8*)&sA[r0 + lr][k0];
            bf16x8 wl = *(const bf16x8*)&sWl[nt * 16 + lr][k0];
            a = __builtin_amdgcn_mfma_f32_16x16x32_bf16(af, wl, a, 0, 0, 0);
        }
        acc[nt] = a;
    }

    if constexpr (!OUTPROJ) {
        ushort* outp = (ushort*)out_p;
#pragma unroll
        for (int nt = 0; nt < 4; ++nt) {
            int col = nt * 16 + lr;
            float bias = bl[col];
#pragma unroll
            for (int r = 0; r < 4; ++r) {
                int row = r0 + quad * 4 + r;  // C/D: col=lane&15, row=(lane>>4)*4+reg
                int g = row0 + row;
                if (g < N_NODES) {
                    float v = acc[nt][r] + bias;
                    v = (v >= 0.f) ? v : alpha * v;
                    outp[(size_t)g * HID + col] = f2bf(v);
                }
            }
        }
    } else {
        // h2 tile (post-PReLU, bf16) into sA (rows are wave-private), then @Wout
#pragma unroll
        for (int nt = 0; nt < 4; ++nt) {
            int col = nt * 16 + lr;
            float bias = bl[col];
#pragma unroll
            for (int r = 0; r < 4; ++r) {
                int row = r0 + quad * 4 + r;
                float v = acc[nt][r] + bias;
                v = (v >= 0.f) ? v : alpha * v;
                sA[row][col] = f2bf(v);
            }
        }
        __syncthreads();
        f32x4 acc2[4];
#pragma unroll
        for (int nt = 0; nt < 4; ++nt) {
            f32x4 a = {0.f, 0.f, 0.f, 0.f};
#pragma unroll
            for (int ks = 0; ks < 2; ++ks) {
                int k0 = ks * 32 + quad * 8;
                bf16x8 hf = *(const bf16x8*)&sA[r0 + lr][k0];
                bf16x8 wo = *(const bf16x8*)&sWo[nt * 16 + lr][k0];
                a = __builtin_amdgcn_mfma_f32_16x16x32_bf16(hf, wo, a, 0, 0, 0);
            }
            acc2[nt] = a;
        }
        float* outp = (float*)out_p;
#pragma unroll
        for (int nt = 0; nt < 4; ++nt) {
            int col = nt * 16 + lr;
            float bias = bo[col];
#pragma unroll
            for (int r = 0; r < 4; ++r) {
                int row = r0 + quad * 4 + r;
                int g = row0 + row;
                if (g < N_NODES)
                    outp[(size_t)g * HID + col] = acc2[nt][r] + bias;
            }
        }
    }
}

extern "C" void kernel_launch(void* const* d_in, const int* in_sizes, int n_in,
                              void* d_out, int out_size, void* d_ws, size_t ws_size,
                              hipStream_t stream) {
    const int*   x    = (const int*)d_in[0];
    const int*   src  = (const int*)d_in[1];
    const int*   dst  = src + N_EDGES;
    const float* emb  = (const float*)d_in[3];
    const float* Wl1  = (const float*)d_in[4];
    const float* bl1  = (const float*)d_in[5];
    const float* Wr1  = (const float*)d_in[6];
    const float* a1   = (const float*)d_in[7];
    const float* Wl2  = (const float*)d_in[8];
    const float* bl2  = (const float*)d_in[9];
    const float* Wr2  = (const float*)d_in[10];
    const float* a2   = (const float*)d_in[11];
    const float* Wout = (const float*)d_in[12];
    const float* bout = (const float*)d_in[13];

    char* ws = (char*)d_ws;
    int*    gh      = (int*)ws;                      // 100,352 (pad 100,416)
    int*    btot    = (int*)(ws + 100416);           // 832
    int*    bstart  = (int*)(ws + 101248);           // 832
    int*    rowptr  = (int*)(ws + 102080);           // 400,064
    ushort* wbf     = (ushort*)(ws + 502144);        // 40,960
    uint*   ebuf    = (uint*)(ws + 543104);          // 5,000,000
    int*    csr_src = (int*)(ws + 5543104);          // 5,000,000
    ushort* h0      = (ushort*)(ws + 10543104);      // 12.8 MB
    ushort* h1      = (ushort*)(ws + 23343104);      // 12.8 MB

    ushort* wl1b  = wbf;
    ushort* wr1b  = wbf + 4096;
    ushort* wl2b  = wbf + 8192;
    ushort* wr2b  = wbf + 12288;
    ushort* woutb = wbf + 16384;

    const int gemm_blocks = (N_NODES + 63) / 64;     // 1563

    prep<<<EMB_BLOCKS + NBLOCK + 5, 256, 0, stream>>>(
        x, emb, h0, dst, gh, Wl1, Wr1, Wl2, Wr2, Wout, wbf);
    p2_scan<<<NB, 128, 0, stream>>>(gh, btot);
    p3_scatter<<<NBLOCK, 256, 0, stream>>>(src, dst, gh, btot, bstart, ebuf);
    p4_csr<<<NB, 256, 0, stream>>>(ebuf, bstart, rowptr, csr_src);

    layer_fused<false><<<gemm_blocks, 256, 0, stream>>>(
        rowptr, csr_src, h0, wl1b, bl1, wr1b, a1, wr1b, bl1, h1);
    layer_fused<true><<<gemm_blocks, 256, 0, stream>>>(
        rowptr, csr_src, h1, wl2b, bl2, wr2b, a2, woutb, bout, d_out);
}